// Round 2
// baseline (9234.740 us; speedup 1.0000x reference)
//
#include <hip/hip_runtime.h>
#include <hip/hip_cooperative_groups.h>

namespace cg = cooperative_groups;

#define NN 4096
#define QQ 2048
#define LDM 8192
#define GOFF 16384  // float offset of G inside ws

// ---------- helpers ----------
__device__ __forceinline__ float erfinv_f(float x){
  float w = -logf((1.0f - x)*(1.0f + x));
  float p;
  if (w < 5.0f) {
    w = w - 2.5f;
    p = 2.81022636e-08f;
    p = fmaf(p, w, 3.43273939e-07f);
    p = fmaf(p, w, -3.5233877e-06f);
    p = fmaf(p, w, -4.39150654e-06f);
    p = fmaf(p, w, 0.00021858087f);
    p = fmaf(p, w, -0.00125372503f);
    p = fmaf(p, w, -0.00417768164f);
    p = fmaf(p, w, 0.246640727f);
    p = fmaf(p, w, 1.50140941f);
  } else {
    w = sqrtf(w) - 3.0f;
    p = -0.000200214257f;
    p = fmaf(p, w, 0.000100950558f);
    p = fmaf(p, w, 0.00134934322f);
    p = fmaf(p, w, -0.00367342844f);
    p = fmaf(p, w, 0.00573950773f);
    p = fmaf(p, w, -0.0076224613f);
    p = fmaf(p, w, 0.00943887047f);
    p = fmaf(p, w, 1.00167406f);
    p = fmaf(p, w, 2.83297682f);
  }
  return p * x;
}

__device__ __forceinline__ float wave_red(float v){
  #pragma unroll
  for (int o = 32; o > 0; o >>= 1) v += __shfl_down(v, o, 64);
  return v;
}

// ---------- one cooperative kernel for the whole pipeline ----------
__global__ __launch_bounds__(256, 2) void k_coop(
    const float* __restrict__ yt, const float* __restrict__ yp,
    const float* __restrict__ p_s2e, const float* __restrict__ p_s2b,
    const float* __restrict__ p_len, const float* __restrict__ dm,
    const int* __restrict__ zi, float* __restrict__ ws, float* __restrict__ out)
{
  cg::grid_group grid = cg::this_grid();
  __shared__ __align__(16) float sh[16384];   // 64 KB union for all phases
  float* scal = ws;
  float* t    = ws + 16;
  float* tt   = ws + 16 + QQ;
  float* rv   = ws + 16 + 2*QQ;
  float* xv   = ws + 16 + 3*QQ;
  float* sc   = ws + 16 + 4*QQ;
  int*   cnt  = (int*)(ws + 16 + 5*QQ);
  float* G    = ws + GOFF;
  const int tid  = threadIdx.x;
  const int bid  = blockIdx.x;
  const int nb   = gridDim.x;
  const int gtid = bid*256 + tid;
  const int gsz  = nb*256;

  // ---- stage 1: per-element stats + bincount ----
  if (gtid < NN) {
    float s2 = p_s2e[0] + p_s2b[0];
    float y  = (yt[gtid]-yp[gtid]) / (0.779696801233676f * sqrtf(s2)) + 0.5772156649015329f;
    float em = __expf(-y);
    float u  = __expf(-em);
    u = fminf(fmaxf(u, 1e-6f), 1.0f - 1e-6f);
    float zs = 1.41421356237309515f * erfinv_f(2.0f*u - 1.0f);
    int q = zi[gtid];
    atomicAdd(&t[q], zs);
    atomicAdd(&cnt[q], 1);
    float r0 = wave_red(y), r1 = wave_red(em), r2 = wave_red(zs*zs);
    if ((tid & 63) == 0) {
      atomicAdd(&scal[0], r0);
      atomicAdd(&scal[1], r1);
      atomicAdd(&scal[2], r2);
    }
  }
  grid.sync();

  // ---- stage 1b: t~ ----
  if (gtid < QQ) {
    int c = cnt[gtid];
    float scf = sqrtf((float)c);
    float tv = (c > 0) ? t[gtid]/scf : 0.0f;
    sc[gtid] = scf; tt[gtid] = tv; rv[gtid] = tv;
    float rd = wave_red(tv*tv);
    if ((tid & 63) == 0) atomicAdd(&scal[3], rd);
  }
  grid.sync();

  // ---- stage 2: build G = sig2e*I + sqrt(c_p c_q)*sig2bs*exp(-M/(2l)) ----
  {
    float inv2l = 0.5f / p_len[0];
    float s2b = p_s2b[0], s2e = p_s2e[0];
    for (int idx = gtid; idx < (QQ*QQ)/4; idx += gsz) {
      int p = idx >> 9;
      int q = (idx & 511) << 2;
      float4 d  = *(const float4*)&dm[(size_t)p*LDM + q];
      float4 s4 = *(const float4*)&sc[q];
      float sp = sc[p]*s2b;
      float4 v;
      v.x = sp*s4.x*__expf(-d.x*inv2l);
      v.y = sp*s4.y*__expf(-d.y*inv2l);
      v.z = sp*s4.z*__expf(-d.z*inv2l);
      v.w = sp*s4.w*__expf(-d.w*inv2l);
      if (p >= q && p < q+4) ((float*)&v)[p-q] += s2e;
      *(float4*)&G[(size_t)p*QQ + q] = v;
    }
  }
  grid.sync();

  // ---- stage 3: blocked Cholesky, NB=128 ----
  for (int s = 0; s < 16; ++s) {
    const int k0 = s*128, m = QQ - k0 - 128;
    if (bid == 0) {
      // --- panel factor (raw outer-product form in LDS, col-major s[j*128+i]) ---
      const int r = tid >> 1, h = tid & 1;
      {
        const float* src = &G[(size_t)(k0+r)*QQ + k0];
        for (int j = h; j <= r; j += 2) sh[j*128 + r] = src[j];
      }
      __syncthreads();
      for (int j = 0; j < 127; ++j) {
        float invd = 1.0f / sh[j*128 + j];
        if (r > j) {
          float ci = sh[j*128 + r] * invd;
          for (int mm = j+1+h; mm <= r; mm += 2) sh[mm*128 + r] -= ci * sh[j*128 + mm];
        }
        __syncthreads();
      }
      // logdet contribution: sum(log raw_jj) = 2*sum(log L_jj)
      if (tid < 128) {
        float lv = __logf(sh[tid*128 + tid]);
        lv = wave_red(lv);
        if ((tid & 63) == 0) atomicAdd(&scal[4], lv);
      }
      if (tid >= 1 && tid < 128) sh[tid*128 + 0] = sqrtf(sh[tid*128 + tid]);
      __syncthreads();
      {
        float d0 = sqrtf(sh[0]);
        float* dst = &G[(size_t)(k0+r)*QQ + k0];
        for (int j = h; j <= r; j += 2) {
          float dj = (j == 0) ? d0 : sh[j*128 + 0];
          dst[j] = (j == r) ? dj : sh[j*128 + r]/dj;
        }
      }
      __syncthreads();

      // --- invert the two 64x64 diagonal blocks of L (W1, W2) ---
      float* l1p = sh;            // packed lower triangular, 2080
      float* l2p = sh + 2080;     // 2080
      float* w1  = sh + 4160;     // 64x65
      float* w2  = sh + 8320;     // 64x65
      if (tid < 128) {
        const int g = tid >> 6, j = tid & 63;
        const int base = k0 + 64*g;
        float* lp = g ? l2p : l1p;
        const float* src = &G[(size_t)(base+j)*QQ + base];
        int ro = j*(j+1)/2;
        for (int jj = 0; jj <= j; ++jj) lp[ro + jj] = src[jj];
      }
      __syncthreads();
      if (tid < 128) {
        const int g = tid >> 6, j = tid & 63;
        float* lp = g ? l2p : l1p;
        float* w  = g ? w2  : w1;
        for (int mm = 0; mm < j; ++mm) w[mm*65 + j] = 0.0f;   // zero upper slots
        w[j*65 + j] = 1.0f / lp[j*(j+1)/2 + j];
        int ro = (j+1)*(j+2)/2;
        for (int i2 = j+1; i2 < 64; ++i2) {
          float acc = 0.0f;
          for (int mm = j; mm < i2; ++mm) acc += lp[ro + mm] * w[mm*65 + j];
          w[i2*65 + j] = -acc / lp[ro + i2];
          ro += i2 + 1;
        }
      }
      __syncthreads();
      if (tid < 128) {  // write W1/W2 over the diag blocks in G
        const int g = tid >> 6, j = tid & 63;
        const int base = k0 + 64*g;
        float* w = g ? w2 : w1;
        for (int idx = j; idx < 64*64; idx += 64) {
          int i = idx >> 6, jj = idx & 63;
          if (jj <= i) G[(size_t)(base+i)*QQ + base + jj] = w[i*65 + jj];
        }
      }
      __syncthreads();

      // --- W21 = -W2 * (L21 * W1), overwrites L21 in G ---
      {
        float* tb = sh;  // 64x65, reuses l1p/l2p region
        const int i = tid & 63, jg = tid >> 6;
        const float* brow = &G[(size_t)(k0+64+i)*QQ + k0];
        float acc[16];
        #pragma unroll
        for (int a = 0; a < 16; ++a) acc[a] = 0.0f;
        for (int mm = 0; mm < 64; ++mm) {
          float bv = brow[mm];
          #pragma unroll
          for (int a = 0; a < 16; ++a) acc[a] += bv * w1[mm*65 + jg*16 + a];
        }
        #pragma unroll
        for (int a = 0; a < 16; ++a) tb[i*65 + jg*16 + a] = acc[a];
        __syncthreads();
        #pragma unroll
        for (int a = 0; a < 16; ++a) acc[a] = 0.0f;
        for (int mm = 0; mm <= i; ++mm) {
          float wv = w2[i*65 + mm];
          #pragma unroll
          for (int a = 0; a < 16; ++a) acc[a] += wv * tb[mm*65 + jg*16 + a];
        }
        float* dst = &G[(size_t)(k0+64+i)*QQ + k0];
        #pragma unroll
        for (int a = 0; a < 16; ++a) dst[jg*16 + a] = -acc[a];
      }
    }
    grid.sync();

    // --- panel TRSM as GEMM: P = A21 * W^T (in place) ---
    if (m > 0) {
      const int nt = m/64;
      float* AT = sh;          // 64x68
      float* WT = sh + 4352;   // 64x132
      for (int rb = bid; rb < nt; rb += nb) {
        const int rowbase = k0 + 128 + 64*rb;
        const int ty = tid >> 4, tx = tid & 15;
        float acc[4][8];
        #pragma unroll
        for (int a = 0; a < 4; ++a)
          #pragma unroll
          for (int b = 0; b < 8; ++b) acc[a][b] = 0.0f;
        for (int kc = 0; kc < 128; kc += 64) {
          for (int idx = tid; idx < 64*64; idx += 256) {
            int mm = idx & 63, ii = idx >> 6;
            AT[mm*68 + ii] = G[(size_t)(rowbase+ii)*QQ + k0 + kc + mm];
          }
          for (int idx = tid; idx < 64*128; idx += 256) {
            int mm = idx & 63, j = idx >> 6;
            WT[mm*132 + j] = (kc + mm <= j) ? G[(size_t)(k0+j)*QQ + k0 + kc + mm] : 0.0f;
          }
          __syncthreads();
          for (int mm = 0; mm < 64; ++mm) {
            float4 av = *(const float4*)&AT[mm*68 + ty*4];
            float4 b0 = *(const float4*)&WT[mm*132 + tx*8];
            float4 b1 = *(const float4*)&WT[mm*132 + tx*8 + 4];
            float avv[4] = {av.x, av.y, av.z, av.w};
            float bvv[8] = {b0.x, b0.y, b0.z, b0.w, b1.x, b1.y, b1.z, b1.w};
            #pragma unroll
            for (int a = 0; a < 4; ++a)
              #pragma unroll
              for (int b = 0; b < 8; ++b) acc[a][b] += avv[a]*bvv[b];
          }
          __syncthreads();
        }
        #pragma unroll
        for (int a = 0; a < 4; ++a)
          #pragma unroll
          for (int b = 0; b < 8; ++b)
            G[(size_t)(rowbase + ty*4 + a)*QQ + k0 + tx*8 + b] = acc[a][b];
      }
    }
    grid.sync();

    // --- trailing SYRK: C -= P P^T on lower-triangle 64x64 tiles ---
    if (m > 0) {
      const int nt = m/64;
      const int ntiles = nt*(nt+1)/2;
      float* PT1 = sh;          // 64x68
      float* PT2 = sh + 4352;   // 64x68
      for (int b2 = bid; b2 < ntiles; b2 += nb) {
        int ti = (int)((sqrtf(8.0f*(float)b2 + 1.0f) - 1.0f)*0.5f);
        while ((ti+1)*(ti+2)/2 <= b2) ++ti;
        while (ti*(ti+1)/2 > b2) --ti;
        int tj = b2 - ti*(ti+1)/2;
        int ibase = k0 + 128 + ti*64, jbase = k0 + 128 + tj*64;
        const int ty = tid >> 4, tx = tid & 15;
        float acc[4][4];
        #pragma unroll
        for (int a = 0; a < 4; ++a)
          #pragma unroll
          for (int c = 0; c < 4; ++c) acc[a][c] = 0.0f;
        for (int kc = 0; kc < 128; kc += 64) {
          for (int idx = tid; idx < 64*64; idx += 256) {
            int mm = idx & 63, ii = idx >> 6;
            PT1[mm*68 + ii] = G[(size_t)(ibase+ii)*QQ + k0 + kc + mm];
            PT2[mm*68 + ii] = G[(size_t)(jbase+ii)*QQ + k0 + kc + mm];
          }
          __syncthreads();
          for (int mm = 0; mm < 64; ++mm) {
            float4 av = *(const float4*)&PT1[mm*68 + ty*4];
            float4 bv = *(const float4*)&PT2[mm*68 + tx*4];
            float avv[4] = {av.x, av.y, av.z, av.w};
            float bvv[4] = {bv.x, bv.y, bv.z, bv.w};
            #pragma unroll
            for (int a = 0; a < 4; ++a)
              #pragma unroll
              for (int c = 0; c < 4; ++c) acc[a][c] += avv[a]*bvv[c];
          }
          __syncthreads();
        }
        #pragma unroll
        for (int a = 0; a < 4; ++a)
          #pragma unroll
          for (int c = 0; c < 4; ++c)
            G[(size_t)(ibase + ty*4 + a)*QQ + jbase + tx*4 + c] -= acc[a][c];
      }
    }
    grid.sync();
  }

  // ---- stage 4: forward solve ----
  for (int s = 0; s < 16; ++s) {
    const int k0 = s*128, m = QQ - k0 - 128;
    if (bid == 0 && tid < 128) {
      const float* row = &G[(size_t)(k0+tid)*QQ + k0];
      float acc = 0.0f;
      for (int j = 0; j <= tid; ++j) acc += row[j]*rv[k0+j];
      xv[k0+tid] = acc;
    }
    grid.sync();
    if (m > 0) {
      if (tid < 128) sh[tid] = xv[k0 + tid];
      __syncthreads();
      for (int i = k0 + 128 + gtid; i < QQ; i += gsz) {
        const float* row = &G[(size_t)i*QQ + k0];
        float acc = 0.0f;
        #pragma unroll 8
        for (int j = 0; j < 128; ++j) acc += row[j]*sh[j];
        rv[i] -= acc;
      }
    }
    grid.sync();
  }

  // ---- stage 5: backward solve ----
  for (int s = 15; s >= 0; --s) {
    const int k0 = s*128;
    if (bid == 0) {
      if (tid < 128) sh[tid] = xv[k0 + tid];
      __syncthreads();
      if (tid < 128) {
        float acc = 0.0f;
        for (int j = tid; j < 128; ++j) acc += G[(size_t)(k0+j)*QQ + k0 + tid]*sh[j];
        xv[k0+tid] = acc;
      }
    }
    grid.sync();
    if (k0 > 0) {
      if (tid < 128) sh[tid] = xv[k0 + tid];
      __syncthreads();
      for (int col = gtid; col < k0; col += gsz) {
        float acc = 0.0f;
        #pragma unroll 8
        for (int r2 = 0; r2 < 128; ++r2) acc += G[(size_t)(k0+r2)*QQ + col]*sh[r2];
        xv[col] -= acc;
      }
    }
    grid.sync();
  }

  // ---- stage 6: dot + final ----
  if (gtid < QQ) {
    float rd = wave_red(tt[gtid]*xv[gtid]);
    if ((tid & 63) == 0) atomicAdd(&scal[5], rd);
  }
  grid.sync();
  if (bid == 0 && tid == 0) {
    float s2e = p_s2e[0], s2b = p_s2b[0], s2 = s2e + s2b;
    const float Nf = 4096.0f, Qf = 2048.0f;
    float mld = 2.0f*scal[0] + 2.0f*scal[1] + Nf*logf(s2) + Nf*logf(0.6079271018540267f);
    float quad = (s2/s2e)*(scal[2] - scal[3] + s2e*scal[5]);
    float logdetR = Nf*logf(s2e) - Nf*logf(s2) - Qf*logf(s2e) + scal[4];
    out[0] = mld + quad - scal[2] + logdetR;
  }
}

// ---------- launch ----------
extern "C" void kernel_launch(void* const* d_in, const int* in_sizes, int n_in,
                              void* d_out, int out_size, void* d_ws, size_t ws_size,
                              hipStream_t stream){
  const float* yt  = (const float*)d_in[0];
  const float* yp  = (const float*)d_in[1];
  const float* s2e = (const float*)d_in[2];
  const float* s2b = (const float*)d_in[3];
  const float* len = (const float*)d_in[4];
  const float* dm  = (const float*)d_in[5];
  const int*   zi  = (const int*)d_in[6];
  float* ws  = (float*)d_ws;
  float* out = (float*)d_out;

  hipMemsetAsync(d_ws, 0, GOFF*sizeof(float), stream);

  int nbpc = 0;
  if (hipOccupancyMaxActiveBlocksPerMultiprocessor(&nbpc, k_coop, 256, 0) != hipSuccess || nbpc < 1)
    nbpc = 1;
  int dev = 0;
  hipGetDevice(&dev);
  int ncu = 0;
  if (hipDeviceGetAttribute(&ncu, hipDeviceAttributeMultiprocessorCount, dev) != hipSuccess || ncu < 1)
    ncu = 256;
  int grid = nbpc * ncu;
  if (grid > 512) grid = 512;

  void* args[] = { (void*)&yt, (void*)&yp, (void*)&s2e, (void*)&s2b, (void*)&len,
                   (void*)&dm, (void*)&zi, (void*)&ws, (void*)&out };
  hipLaunchCooperativeKernel(k_coop, dim3(grid), dim3(256), args, 0, stream);
}

// Round 3
// 7375.479 us; speedup vs baseline: 1.2521x; 1.2521x over previous
//
#include <hip/hip_runtime.h>

#define NN 4096
#define QQ 2048
#define LDM 8192
#define GOFF 16384  // float offset of G inside ws

// flags layout (ints) at ws+12304
#define FL_BASE 12304
#define FL_PF   0     // pf[16]   panel done
#define FL_TF   16    // tf[16*32] trsm tile done
#define FL_C3   528   // cnt3[16]  head syrk tiles done
#define FL_CA   544   // cnt_all[16] all syrk tiles done
#define FL_FF   560   // fwd-solve stage done
#define FL_BF   576   // bwd-solve stage done
#define FL_CD   592   // bwd blocks completed

// ---------- helpers ----------
__device__ __forceinline__ float erfinv_f(float x){
  float w = -logf((1.0f - x)*(1.0f + x));
  float p;
  if (w < 5.0f) {
    w = w - 2.5f;
    p = 2.81022636e-08f;
    p = fmaf(p, w, 3.43273939e-07f);
    p = fmaf(p, w, -3.5233877e-06f);
    p = fmaf(p, w, -4.39150654e-06f);
    p = fmaf(p, w, 0.00021858087f);
    p = fmaf(p, w, -0.00125372503f);
    p = fmaf(p, w, -0.00417768164f);
    p = fmaf(p, w, 0.246640727f);
    p = fmaf(p, w, 1.50140941f);
  } else {
    w = sqrtf(w) - 3.0f;
    p = -0.000200214257f;
    p = fmaf(p, w, 0.000100950558f);
    p = fmaf(p, w, 0.00134934322f);
    p = fmaf(p, w, -0.00367342844f);
    p = fmaf(p, w, 0.00573950773f);
    p = fmaf(p, w, -0.0076224613f);
    p = fmaf(p, w, 0.00943887047f);
    p = fmaf(p, w, 1.00167406f);
    p = fmaf(p, w, 2.83297682f);
  }
  return p * x;
}

__device__ __forceinline__ float wave_red(float v){
  #pragma unroll
  for (int o = 32; o > 0; o >>= 1) v += __shfl_down(v, o, 64);
  return v;
}

__device__ __forceinline__ void blk_wait_ge(int* p, int tgt){
  if (threadIdx.x == 0){
    while (__hip_atomic_load(p, __ATOMIC_ACQUIRE, __HIP_MEMORY_SCOPE_AGENT) < tgt)
      __builtin_amdgcn_s_sleep(2);
  }
  __syncthreads();
}

__device__ __forceinline__ void blk_release(int* p, int v){
  __syncthreads();   // all prior LDS+global ops of the block drained (vmcnt before barrier)
  if (threadIdx.x == 0)
    __hip_atomic_store(p, v, __ATOMIC_RELEASE, __HIP_MEMORY_SCOPE_AGENT);
}

// ---------- stage 1: per-element stats, bincount ----------
__global__ void k_stats(const float* yt, const float* yp, const float* p_s2e, const float* p_s2b,
                        const int* zi, float* scal, float* t, int* cnt){
  int i = blockIdx.x*blockDim.x + threadIdx.x;
  float s2 = p_s2e[0] + p_s2b[0];
  float y  = (yt[i]-yp[i]) / (0.779696801233676f * sqrtf(s2)) + 0.5772156649015329f;
  float em = __expf(-y);
  float u  = __expf(-em);
  u = fminf(fmaxf(u, 1e-6f), 1.0f - 1e-6f);
  float zs = 1.41421356237309515f * erfinv_f(2.0f*u - 1.0f);
  int q = zi[i];
  atomicAdd(&t[q], zs);
  atomicAdd(&cnt[q], 1);
  float r0 = wave_red(y), r1 = wave_red(em), r2 = wave_red(zs*zs);
  if ((threadIdx.x & 63) == 0) {
    atomicAdd(&scal[0], r0);
    atomicAdd(&scal[1], r1);
    atomicAdd(&scal[2], r2);
  }
}

__global__ void k_make_tt(const float* t, const int* cnt, float* tt, float* rv, float* sc, float* scal){
  int q = blockIdx.x*blockDim.x + threadIdx.x;
  int c = cnt[q];
  float scf = sqrtf((float)c);
  float tv = (c > 0) ? t[q]/scf : 0.0f;
  sc[q] = scf; tt[q] = tv; rv[q] = tv;
  float rd = wave_red(tv*tv);
  if ((threadIdx.x & 63) == 0) atomicAdd(&scal[3], rd);
}

// ---------- stage 2: build G ----------
__global__ void k_build_G(const float* __restrict__ dm, const float* __restrict__ sc,
                          const float* p_s2e, const float* p_s2b, const float* p_len,
                          float* __restrict__ G){
  int idx = blockIdx.x*blockDim.x + threadIdx.x;   // one float4 per thread
  int p = idx >> 9;
  int q = (idx & 511) << 2;
  float inv2l = 0.5f / p_len[0];
  float4 d  = *(const float4*)&dm[(size_t)p*LDM + q];
  float4 s4 = *(const float4*)&sc[q];
  float sp = sc[p]*p_s2b[0];
  float4 v;
  v.x = sp*s4.x*__expf(-d.x*inv2l);
  v.y = sp*s4.y*__expf(-d.y*inv2l);
  v.z = sp*s4.z*__expf(-d.z*inv2l);
  v.w = sp*s4.w*__expf(-d.w*inv2l);
  if (p >= q && p < q+4) ((float*)&v)[p-q] += p_s2e[0];
  *(float4*)&G[(size_t)p*QQ + q] = v;
}

// ---------- stage 3: whole blocked Cholesky in ONE kernel, flag-based dataflow ----------
__global__ __launch_bounds__(256, 2) void k_chol(float* __restrict__ G, float* scal, int* fl){
  __shared__ __align__(16) float sh[16384];   // 64 KB
  const int tid = threadIdx.x, bid = blockIdx.x, nb = gridDim.x;
  int* pf = fl + FL_PF;
  int* tf = fl + FL_TF;
  int* c3 = fl + FL_C3;
  int* ca = fl + FL_CA;

  for (int s = 0; s < 16; ++s){
    const int k0 = s*128, m = QQ - k0 - 128, nt = m/64, ntiles = nt*(nt+1)/2;
    const int ntprev = (m + 128)/64;                 // nt of stage s-1
    const int ntilesprev = ntprev*(ntprev+1)/2;

    if (bid == 0){
      if (s > 0) blk_wait_ge(&c3[s-1], 3);           // only head tiles gate the panel
      // --- panel factor (raw outer-product, col-major sh[j*128+i]) ---
      const int r = tid >> 1, h = tid & 1;
      {
        const float* src = &G[(size_t)(k0+r)*QQ + k0];
        for (int j = h; j <= r; j += 2) sh[j*128 + r] = src[j];
      }
      __syncthreads();
      for (int j = 0; j < 127; ++j) {
        float invd = 1.0f / sh[j*128 + j];
        if (r > j) {
          float ci = sh[j*128 + r] * invd;
          for (int mm = j+1+h; mm <= r; mm += 2) sh[mm*128 + r] -= ci * sh[j*128 + mm];
        }
        __syncthreads();
      }
      if (tid < 128) {                                // logdet: sum(log raw_jj)
        float lv = wave_red(__logf(sh[tid*128 + tid]));
        if ((tid & 63) == 0) atomicAdd(&scal[4], lv);
      }
      if (tid >= 1 && tid < 128) sh[tid*128 + 0] = sqrtf(sh[tid*128 + tid]);
      __syncthreads();
      {
        float d0 = sqrtf(sh[0]);
        float* dst = &G[(size_t)(k0+r)*QQ + k0];
        for (int j = h; j <= r; j += 2) {
          float dj = (j == 0) ? d0 : sh[j*128 + 0];
          dst[j] = (j == r) ? dj : sh[j*128 + r]/dj;
        }
      }
      __syncthreads();

      // --- invert the two 64x64 diag blocks of L -> W1, W2 ---
      float* l1p = sh;            // packed lower tri, 2080
      float* l2p = sh + 2080;
      float* w1  = sh + 4160;     // 64x65
      float* w2  = sh + 8320;     // 64x65
      if (tid < 128) {
        const int g = tid >> 6, j = tid & 63;
        const int base = k0 + 64*g;
        float* lp = g ? l2p : l1p;
        const float* src = &G[(size_t)(base+j)*QQ + base];
        int ro = j*(j+1)/2;
        for (int jj = 0; jj <= j; ++jj) lp[ro + jj] = src[jj];
      }
      __syncthreads();
      if (tid < 128) {
        const int g = tid >> 6, j = tid & 63;
        float* lp = g ? l2p : l1p;
        float* w  = g ? w2  : w1;
        for (int mm = 0; mm < j; ++mm) w[mm*65 + j] = 0.0f;
        w[j*65 + j] = 1.0f / lp[j*(j+1)/2 + j];
        int ro = (j+1)*(j+2)/2;
        for (int i2 = j+1; i2 < 64; ++i2) {
          float acc = 0.0f;
          for (int mm = j; mm < i2; ++mm) acc += lp[ro + mm] * w[mm*65 + j];
          w[i2*65 + j] = -acc / lp[ro + i2];
          ro += i2 + 1;
        }
      }
      __syncthreads();
      if (tid < 128) {   // write W1/W2 over the diag blocks in G
        const int g = tid >> 6, j = tid & 63;
        const int base = k0 + 64*g;
        float* w = g ? w2 : w1;
        for (int idx = j; idx < 64*64; idx += 64) {
          int i = idx >> 6, jj = idx & 63;
          if (jj <= i) G[(size_t)(base+i)*QQ + base + jj] = w[i*65 + jj];
        }
      }
      __syncthreads();

      // --- W21 = -W2 * (L21 * W1), overwrites L21 ---
      {
        float* tb = sh;   // reuses l1p/l2p region
        const int i = tid & 63, jg = tid >> 6;
        const float* brow = &G[(size_t)(k0+64+i)*QQ + k0];
        float acc[16];
        #pragma unroll
        for (int a = 0; a < 16; ++a) acc[a] = 0.0f;
        for (int mm = 0; mm < 64; ++mm) {
          float bv = brow[mm];
          #pragma unroll
          for (int a = 0; a < 16; ++a) acc[a] += bv * w1[mm*65 + jg*16 + a];
        }
        #pragma unroll
        for (int a = 0; a < 16; ++a) tb[i*65 + jg*16 + a] = acc[a];
        __syncthreads();
        #pragma unroll
        for (int a = 0; a < 16; ++a) acc[a] = 0.0f;
        for (int mm = 0; mm <= i; ++mm) {
          float wv = w2[i*65 + mm];
          #pragma unroll
          for (int a = 0; a < 16; ++a) acc[a] += wv * tb[mm*65 + jg*16 + a];
        }
        float* dst = &G[(size_t)(k0+64+i)*QQ + k0];
        #pragma unroll
        for (int a = 0; a < 16; ++a) dst[jg*16 + a] = -acc[a];
      }
      blk_release(&pf[s], 1);
    }
    else if (bid-1 < nt){
      // --- one TRSM tile: P = A21 * W^T over 64 rows x 128 cols ---
      if (s > 0) blk_wait_ge(&ca[s-1], ntilesprev);
      blk_wait_ge(&pf[s], 1);
      float* AT = sh;          // 64x68
      float* WT = sh + 4352;   // 64x132
      const int rowbase = k0 + 128 + 64*(bid-1);
      const int ty = tid >> 4, tx = tid & 15;
      float acc[4][8];
      #pragma unroll
      for (int a = 0; a < 4; ++a)
        #pragma unroll
        for (int b = 0; b < 8; ++b) acc[a][b] = 0.0f;
      for (int kc = 0; kc < 128; kc += 64) {
        for (int idx = tid; idx < 64*64; idx += 256) {
          int mm = idx & 63, ii = idx >> 6;
          AT[mm*68 + ii] = G[(size_t)(rowbase+ii)*QQ + k0 + kc + mm];
        }
        for (int idx = tid; idx < 64*128; idx += 256) {
          int mm = idx & 63, j = idx >> 6;
          WT[mm*132 + j] = (kc + mm <= j) ? G[(size_t)(k0+j)*QQ + k0 + kc + mm] : 0.0f;
        }
        __syncthreads();
        for (int mm = 0; mm < 64; ++mm) {
          float4 av = *(const float4*)&AT[mm*68 + ty*4];
          float4 b0 = *(const float4*)&WT[mm*132 + tx*8];
          float4 b1 = *(const float4*)&WT[mm*132 + tx*8 + 4];
          float avv[4] = {av.x, av.y, av.z, av.w};
          float bvv[8] = {b0.x, b0.y, b0.z, b0.w, b1.x, b1.y, b1.z, b1.w};
          #pragma unroll
          for (int a = 0; a < 4; ++a)
            #pragma unroll
            for (int b = 0; b < 8; ++b) acc[a][b] += avv[a]*bvv[b];
        }
        __syncthreads();
      }
      #pragma unroll
      for (int a = 0; a < 4; ++a)
        #pragma unroll
        for (int b = 0; b < 8; ++b)
          G[(size_t)(rowbase + ty*4 + a)*QQ + k0 + tx*8 + b] = acc[a][b];
      blk_release(&tf[s*32 + (bid-1)], 1);
    }

    // --- SYRK tiles: C -= P P^T, gated per-tile on the two TRSM flags ---
    {
      float* PT1 = sh;          // 64x68
      float* PT2 = sh + 4352;   // 64x68
      for (int b2 = bid; b2 < ntiles; b2 += nb) {
        int ti = (int)((sqrtf(8.0f*(float)b2 + 1.0f) - 1.0f)*0.5f);
        while ((ti+1)*(ti+2)/2 <= b2) ++ti;
        while (ti*(ti+1)/2 > b2) --ti;
        int tj = b2 - ti*(ti+1)/2;
        blk_wait_ge(&tf[s*32 + ti], 1);
        if (tj != ti) blk_wait_ge(&tf[s*32 + tj], 1);
        int ibase = k0 + 128 + ti*64, jbase = k0 + 128 + tj*64;
        const int ty = tid >> 4, tx = tid & 15;
        float acc[4][4];
        #pragma unroll
        for (int a = 0; a < 4; ++a)
          #pragma unroll
          for (int c = 0; c < 4; ++c) acc[a][c] = 0.0f;
        for (int kc = 0; kc < 128; kc += 64) {
          for (int idx = tid; idx < 64*64; idx += 256) {
            int mm = idx & 63, ii = idx >> 6;
            PT1[mm*68 + ii] = G[(size_t)(ibase+ii)*QQ + k0 + kc + mm];
            PT2[mm*68 + ii] = G[(size_t)(jbase+ii)*QQ + k0 + kc + mm];
          }
          __syncthreads();
          for (int mm = 0; mm < 64; ++mm) {
            float4 av = *(const float4*)&PT1[mm*68 + ty*4];
            float4 bv = *(const float4*)&PT2[mm*68 + tx*4];
            float avv[4] = {av.x, av.y, av.z, av.w};
            float bvv[4] = {bv.x, bv.y, bv.z, bv.w};
            #pragma unroll
            for (int a = 0; a < 4; ++a)
              #pragma unroll
              for (int c = 0; c < 4; ++c) acc[a][c] += avv[a]*bvv[c];
          }
          __syncthreads();
        }
        #pragma unroll
        for (int a = 0; a < 4; ++a)
          #pragma unroll
          for (int c = 0; c < 4; ++c)
            G[(size_t)(ibase + ty*4 + a)*QQ + jbase + tx*4 + c] -= acc[a][c];
        __syncthreads();   // drain writes before signaling
        if (tid == 0){
          if (b2 < 3) __hip_atomic_fetch_add(&c3[s], 1, __ATOMIC_RELEASE, __HIP_MEMORY_SCOPE_AGENT);
          __hip_atomic_fetch_add(&ca[s], 1, __ATOMIC_RELEASE, __HIP_MEMORY_SCOPE_AGENT);
        }
      }
    }
  }
}

// ---------- stage 4: forward solve, 16 blocks chained by flags ----------
__global__ __launch_bounds__(128) void k_fwd(const float* __restrict__ G, const float* __restrict__ rv,
                                             float* __restrict__ xv, int* fl){
  int* ff = fl + FL_FF;
  const int s = blockIdx.x, k0 = s*128, i = threadIdx.x;
  __shared__ float sx[128];
  __shared__ float sr[128];
  float r = rv[k0+i];
  for (int j = 0; j < s; ++j){
    blk_wait_ge(&ff[j], 1);
    sx[i] = xv[j*128 + i];
    __syncthreads();
    const float* row = &G[(size_t)(k0+i)*QQ + j*128];
    float acc = 0.0f;
    #pragma unroll 8
    for (int mm = 0; mm < 128; ++mm) acc += row[mm]*sx[mm];
    r -= acc;
  }
  sr[i] = r;
  __syncthreads();
  const float* wrow = &G[(size_t)(k0+i)*QQ + k0];   // W = inv(L_kk), lower layout
  float acc = 0.0f;
  for (int j = 0; j <= i; ++j) acc += wrow[j]*sr[j];
  xv[k0+i] = acc;
  blk_release(&ff[s], 1);
}

// ---------- stage 5: backward solve + dot + final, 16 blocks chained ----------
__global__ __launch_bounds__(128) void k_bwd(const float* __restrict__ G, const float* __restrict__ tt,
                                             const float* __restrict__ xv, float* __restrict__ yv,
                                             float* scal, const float* p_s2e, const float* p_s2b,
                                             float* out, int* fl){
  int* bf = fl + FL_BF;
  int* cd = fl + FL_CD;
  const int s = blockIdx.x, k0 = s*128, i = threadIdx.x;
  __shared__ float sx[128];
  __shared__ float sr[128];
  float r = xv[k0+i];
  for (int j = 15; j > s; --j){
    blk_wait_ge(&bf[j], 1);
    sx[i] = yv[j*128 + i];
    __syncthreads();
    const float* col = &G[(size_t)(j*128)*QQ + k0 + i];
    float acc = 0.0f;
    #pragma unroll 4
    for (int mm = 0; mm < 128; ++mm) acc += col[(size_t)mm*QQ]*sx[mm];
    r -= acc;
  }
  sr[i] = r;
  __syncthreads();
  float acc = 0.0f;                                  // y = W^T r  (column access of W)
  for (int j = i; j < 128; ++j) acc += G[(size_t)(k0+j)*QQ + k0 + i]*sr[j];
  yv[k0+i] = acc;
  float pd = wave_red(tt[k0+i]*acc);
  if ((i & 63) == 0) atomicAdd(&scal[5], pd);
  blk_release(&bf[s], 1);
  if (i == 0) __hip_atomic_fetch_add(cd, 1, __ATOMIC_RELEASE, __HIP_MEMORY_SCOPE_AGENT);
  if (s == 0 && i == 0){
    while (__hip_atomic_load(cd, __ATOMIC_ACQUIRE, __HIP_MEMORY_SCOPE_AGENT) < 16)
      __builtin_amdgcn_s_sleep(2);
    float s2e = p_s2e[0], s2b = p_s2b[0], s2v = s2e + s2b;
    const float Nf = 4096.0f, Qf = 2048.0f;
    float mld = 2.0f*scal[0] + 2.0f*scal[1] + Nf*logf(s2v) + Nf*logf(0.6079271018540267f);
    float quad = (s2v/s2e)*(scal[2] - scal[3] + s2e*scal[5]);
    float logdetR = Nf*logf(s2e) - Nf*logf(s2v) - Qf*logf(s2e) + scal[4];
    out[0] = mld + quad - scal[2] + logdetR;
  }
}

// ---------- launch ----------
extern "C" void kernel_launch(void* const* d_in, const int* in_sizes, int n_in,
                              void* d_out, int out_size, void* d_ws, size_t ws_size,
                              hipStream_t stream){
  const float* yt  = (const float*)d_in[0];
  const float* yp  = (const float*)d_in[1];
  const float* s2e = (const float*)d_in[2];
  const float* s2b = (const float*)d_in[3];
  const float* len = (const float*)d_in[4];
  const float* dm  = (const float*)d_in[5];
  const int*   zi  = (const int*)d_in[6];
  float* ws   = (float*)d_ws;
  float* scal = ws;
  float* t    = ws + 16;            // reused as yv in k_bwd
  float* tt   = ws + 16 + QQ;
  float* rv   = ws + 16 + 2*QQ;
  float* xv   = ws + 16 + 3*QQ;
  float* sc   = ws + 16 + 4*QQ;
  int*   cnt  = (int*)(ws + 16 + 5*QQ);
  int*   fl   = (int*)(ws + FL_BASE);
  float* G    = ws + GOFF;
  float* out  = (float*)d_out;

  hipMemsetAsync(d_ws, 0, GOFF*sizeof(float), stream);
  k_stats  <<<NN/256, 256, 0, stream>>>(yt, yp, s2e, s2b, zi, scal, t, cnt);
  k_make_tt<<<QQ/256, 256, 0, stream>>>(t, cnt, tt, rv, sc, scal);
  k_build_G<<<(QQ*QQ)/(4*256), 256, 0, stream>>>(dm, sc, s2e, s2b, len, G);

  int nbpc = 0;
  if (hipOccupancyMaxActiveBlocksPerMultiprocessor(&nbpc, k_chol, 256, 0) != hipSuccess || nbpc < 1)
    nbpc = 1;
  int dev = 0;
  hipGetDevice(&dev);
  int ncu = 0;
  if (hipDeviceGetAttribute(&ncu, hipDeviceAttributeMultiprocessorCount, dev) != hipSuccess || ncu < 1)
    ncu = 256;
  int grid = nbpc * ncu;
  if (grid > 512) grid = 512;
  void* args[] = { (void*)&G, (void*)&scal, (void*)&fl };
  hipLaunchCooperativeKernel(k_chol, dim3(grid), dim3(256), args, 0, stream);

  k_fwd<<<16, 128, 0, stream>>>(G, rv, xv, fl);
  k_bwd<<<16, 128, 0, stream>>>(G, tt, xv, t, scal, s2e, s2b, out, fl);
}